// Round 10
// baseline (10185.184 us; speedup 1.0000x reference)
//
#include <hip/hip_runtime.h>
#include <cmath>

// ---------------------------------------------------------------------------
// DeepAR sampling on MI355X. Round 10: sample-resident persistent decoder.
// KEY INSIGHT: decoder chains are independent per sample (no cross-sample
// ops in the reference). One block owns 32 samples for all 48 steps:
//  - h resident in LDS (fp16 2-plane, double-buffered, 128 KB of 160 KB/CU)
//  - weights streamed from per-XCD L2 (full Wr 3.1 MB <= 4 MB, shared by
//    all blocks on the XCD); NO h HBM round trip, NO grid barriers, NO
//    per-step launches. 256 blocks x 256 threads, 1 block/CU.
//  - bit-exact vs round 9: same plane bits, same per-acc MFMA sequences,
//    same butterfly trees, per-jb head partials reduced jb-ascending.
//  - encoder: blocks co-located on one XCD (launch 384, workers b%8==0) so
//    the flag-barrier round trip is L2-hit instead of cross-die.
// ---------------------------------------------------------------------------

#define JAX_PARTITIONABLE 1

#define HIDDEN 512
#define EMB 40
#define HIST 336
#define PRED 48
#define S_N 8192
#define ENC_BLOCKS 48

#define WPLANE (1536 * 512)     // shorts per W split plane
#define INV4096 (1.0f / 4096.0f)

typedef __attribute__((ext_vector_type(8))) _Float16 half8;
typedef __attribute__((ext_vector_type(4))) float f32x4;

// ------------------------------- threefry ----------------------------------
struct KeyPair { unsigned a, b; };

__device__ __forceinline__ unsigned rotl32_(unsigned v, unsigned s) {
  return (v << s) | (v >> (32u - s));
}

__device__ __forceinline__ KeyPair tf2x32(KeyPair k, unsigned x0, unsigned x1) {
  unsigned ks0 = k.a, ks1 = k.b, ks2 = ks0 ^ ks1 ^ 0x1BD11BDAu;
  x0 += ks0; x1 += ks1;
#define TF_R(r) { x0 += x1; x1 = rotl32_(x1, r); x1 ^= x0; }
  TF_R(13u) TF_R(15u) TF_R(26u) TF_R(6u)  x0 += ks1; x1 += ks2 + 1u;
  TF_R(17u) TF_R(29u) TF_R(16u) TF_R(24u) x0 += ks2; x1 += ks0 + 2u;
  TF_R(13u) TF_R(15u) TF_R(26u) TF_R(6u)  x0 += ks0; x1 += ks1 + 3u;
  TF_R(17u) TF_R(29u) TF_R(16u) TF_R(24u) x0 += ks1; x1 += ks2 + 4u;
  TF_R(13u) TF_R(15u) TF_R(26u) TF_R(6u)  x0 += ks2; x1 += ks0 + 5u;
#undef TF_R
  KeyPair r; r.a = x0; r.b = x1; return r;
}

__device__ __forceinline__ void split2_(KeyPair key, KeyPair& r0, KeyPair& r1) {
#if JAX_PARTITIONABLE
  r0 = tf2x32(key, 0u, 0u);
  r1 = tf2x32(key, 0u, 1u);
#else
  KeyPair p0 = tf2x32(key, 0u, 2u);
  KeyPair p1 = tf2x32(key, 1u, 3u);
  r0.a = p0.a; r0.b = p1.a;
  r1.a = p0.b; r1.b = p1.b;
#endif
}

__device__ __forceinline__ void split3_(KeyPair key, KeyPair& r0, KeyPair& r1, KeyPair& r2) {
#if JAX_PARTITIONABLE
  r0 = tf2x32(key, 0u, 0u);
  r1 = tf2x32(key, 0u, 1u);
  r2 = tf2x32(key, 0u, 2u);
#else
  KeyPair p0 = tf2x32(key, 0u, 3u);
  KeyPair p1 = tf2x32(key, 1u, 4u);
  KeyPair p2 = tf2x32(key, 2u, 5u);
  r0.a = p0.a; r0.b = p1.a;
  r1.a = p2.a; r1.b = p0.b;
  r2.a = p1.b; r2.b = p2.b;
#endif
}

__device__ __forceinline__ unsigned scalar_bits_(KeyPair key) {
#if JAX_PARTITIONABLE
  KeyPair p = tf2x32(key, 0u, 0u);
  return p.a ^ p.b;
#else
  return tf2x32(key, 0u, 0u).a;
#endif
}

__device__ __forceinline__ unsigned batch_bits_8192_(KeyPair key, int s) {
#if JAX_PARTITIONABLE
  KeyPair p = tf2x32(key, 0u, (unsigned)s);
  return p.a ^ p.b;
#else
  if (s < 4096) return tf2x32(key, (unsigned)s, (unsigned)(4096 + s)).a;
  return tf2x32(key, (unsigned)(s - 4096), (unsigned)s).b;
#endif
}

__device__ __forceinline__ KeyPair subkey_of_8192_(KeyPair key, int s) {
#if JAX_PARTITIONABLE
  return tf2x32(key, 0u, (unsigned)s);
#else
  KeyPair r;
  if (s < 4096) {
    r.a = tf2x32(key, (unsigned)(2 * s),     (unsigned)(8192 + 2 * s)).a;
    r.b = tf2x32(key, (unsigned)(2 * s + 1), (unsigned)(8192 + 2 * s + 1)).a;
  } else {
    int m = 2 * s - 8192;
    r.a = tf2x32(key, (unsigned)m,       (unsigned)(m + 8192)).b;
    r.b = tf2x32(key, (unsigned)(m + 1), (unsigned)(m + 1 + 8192)).b;
  }
  return r;
#endif
}

// ------------------------- fp32 numerics (XLA-matched) ---------------------
__device__ __forceinline__ float acc_logf_(float x) {
  return (float)log((double)x);
}
__device__ __forceinline__ float acc_expf_(float x) {
  return (float)exp((double)x);
}

__device__ __forceinline__ float bits_to_uniform01_(unsigned bits) {
  return __uint_as_float((bits >> 9) | 0x3F800000u) - 1.0f;
}

__device__ __forceinline__ float xla_log1pf_(float t) {
  #pragma clang fp contract(off)
  float small_ = (1.0f + (-0.5f) * t) * t;
  float large_ = acc_logf_(t + 1.0f);
  return (fabsf(t) < 1e-4f) ? small_ : large_;
}

__device__ float xla_erfinv_(float x) {
  #pragma clang fp contract(off)
  float w = -xla_log1pf_(-(x * x));
  float p;
  if (w < 5.0f) {
    float ww = w - 2.5f;
    p = 2.81022636e-08f;
    p = 3.43273939e-07f + p * ww;
    p = -3.5233877e-06f + p * ww;
    p = -4.39150654e-06f + p * ww;
    p = 0.00021858087f + p * ww;
    p = -0.00125372503f + p * ww;
    p = -0.00417768164f + p * ww;
    p = 0.246640727f + p * ww;
    p = 1.50140941f + p * ww;
  } else {
    float ww = sqrtf(w) - 3.0f;
    p = -0.000200214257f;
    p = 0.000100950558f + p * ww;
    p = 0.00134934322f + p * ww;
    p = -0.00367342844f + p * ww;
    p = 0.00573950773f + p * ww;
    p = -0.0076224613f + p * ww;
    p = 0.00943887047f + p * ww;
    p = 1.00167406f + p * ww;
    p = 2.83297682f + p * ww;
  }
  return p * x;
}

__device__ float bits_to_normal_(unsigned bits) {
  #pragma clang fp contract(off)
  const float lo = __uint_as_float(0xBF7FFFFFu);
  float f = bits_to_uniform01_(bits);
  float u = f * 2.0f + lo;
  u = fmaxf(lo, u);
  return __uint_as_float(0x3FB504F3u) * xla_erfinv_(u);
}

__device__ __forceinline__ float softplus_(float x) {
  #pragma clang fp contract(off)
  float amax = fmaxf(x, 0.0f);
  float e = acc_expf_(-fabsf(x));
  return amax + xla_log1pf_(e);
}

__device__ __forceinline__ float sigmoid_(float v) { return 1.0f / (1.0f + expf(-v)); }

// fp16 split helpers (round-to-nearest-even via cast)
__device__ __forceinline__ unsigned short f2h_(float f) {
  _Float16 h = (_Float16)f;
  return __builtin_bit_cast(unsigned short, h);
}
__device__ __forceinline__ float h2f_(unsigned short b) {
  return (float)__builtin_bit_cast(_Float16, b);
}

// ------------------------- gamma / student-t sampler -----------------------
__device__ float gamma_sample_(KeyPair gkey, float alpha) {
  #pragma clang fp contract(off)
  const float third = 0.33333334f;
  float d = alpha - third;
  float c = third / sqrtf(d);
  KeyPair key, boost_sub;
  split2_(gkey, key, boost_sub);
  (void)boost_sub;
  float X = 0.0f, V = 1.0f, U = 2.0f;
  for (int guard = 0; guard < 1024; guard++) {
    float X2 = X * X;
    float sq = 1.0f - 0.0331f * (X2 * X2);
    bool cont = false;
    if (U >= sq) {
      float lhs = acc_logf_(U);
      float rhs = (X * 0.5f) + (d * ((1.0f - V) + acc_logf_(V)));
      cont = (lhs >= rhs);
    }
    if (!cont) break;
    KeyPair nkey, xkey, Ukey;
    split3_(key, nkey, xkey, Ukey);
    key = nkey;
    float x, v;
    KeyPair kk = xkey;
    do {
      KeyPair knew, sub;
      split2_(kk, knew, sub);
      kk = knew;
      x = bits_to_normal_(scalar_bits_(sub));
      v = 1.0f + x * c;
    } while (v <= 0.0f);
    X = x * x;
    V = (v * v) * v;
    U = bits_to_uniform01_(scalar_bits_(Ukey));
  }
  return d * V;
}

__device__ float sample_t_eps_(int k, int s, float df) {
  #pragma clang fp contract(off)
  KeyPair base; base.a = 0u; base.b = 42u;
  KeyPair tkey = tf2x32(base, 0u, (unsigned)k);
  KeyPair key_n, key_g;
  split2_(tkey, key_n, key_g);
  float n = bits_to_normal_(batch_bits_8192_(key_n, s));
  KeyPair gkey = subkey_of_8192_(key_g, s);
  float half_df = df * 0.5f;
  float g = gamma_sample_(gkey, half_df);
  return n * sqrtf(half_df / g);
}

// ------------------------------- kernels -----------------------------------

__global__ __launch_bounds__(256) void prep_kernel(
    const float* __restrict__ x, const float* __restrict__ x_mark,
    const float* __restrict__ y_mark, const float* __restrict__ W_emb,
    const float* __restrict__ b_emb, float* __restrict__ scale_p,
    float* __restrict__ tfe, float* __restrict__ emb_y,
    unsigned* __restrict__ flags) {
  int tid = threadIdx.x;
  if (tid == 0) {
    float s = 0.0f;
    for (int t = 0; t < HIST; t++) s += fabsf(x[t]);
    float m = s / 336.0f;
    scale_p[0] = fmaxf(m, 1e-5f);
  }
  for (int i = tid; i < ENC_BLOCKS * 16; i += 256) flags[i] = 0u;
  for (int idx = tid; idx < HIST * EMB; idx += 256) {
    int t = idx / EMB, e = idx % EMB;
    float a = b_emb[e];
    for (int f = 0; f < 4; f++) a += x_mark[t * 4 + f] * W_emb[e * 4 + f];
    tfe[idx] = a;
  }
  for (int idx = tid; idx < PRED * EMB; idx += 256) {
    int kk = idx / EMB, e = idx % EMB;
    float a = b_emb[e];
    for (int f = 0; f < 4; f++) a += y_mark[kk * 4 + f] * W_emb[e * 4 + f];
    emb_y[idx] = a;
  }
}

__global__ __launch_bounds__(256) void enc_gi_kernel(
    const float* __restrict__ x, const float* __restrict__ tfe,
    const float* __restrict__ W_ih, const float* __restrict__ b_ih,
    const float* __restrict__ scale_p, float* __restrict__ enc_gi) {
  __shared__ float fe[EMB];
  __shared__ float xs_s;
  int t = blockIdx.x;
  int tid = threadIdx.x;
  if (tid < EMB) fe[tid] = tfe[t * EMB + tid];
  if (tid == 0) xs_s = x[t] / scale_p[0];
  __syncthreads();
  float xs = xs_s;
  for (int r = tid; r < 3 * HIDDEN; r += 256) {
    const float* wr = W_ih + (size_t)r * 41;
    float a = b_ih[r] + wr[0] * xs;
    #pragma unroll
    for (int e = 0; e < EMB; e++) a += wr[1 + e] * fe[e];
    enc_gi[(size_t)t * 1536 + r] = a;
  }
}

__global__ __launch_bounds__(256) void giy_kernel(
    const float* __restrict__ emb_y, const float* __restrict__ W_ih,
    const float* __restrict__ b_ih, float* __restrict__ giy) {
  __shared__ float fe[EMB];
  int k = blockIdx.x;
  int tid = threadIdx.x;
  if (tid < EMB) fe[tid] = emb_y[k * EMB + tid];
  __syncthreads();
  for (int r = tid; r < 3 * HIDDEN; r += 256) {
    const float* wr = W_ih + (size_t)r * 41;
    float a = b_ih[r];
    #pragma unroll
    for (int e = 0; e < EMB; e++) a += wr[1 + e] * fe[e];
    giy[(size_t)k * 1536 + r] = a;
  }
}

// W_hh -> 2 fp16 split planes: Wr[sp][jb*96 + g*32 + jl][k], row = g*512+jb*32+jl
__global__ __launch_bounds__(256) void wsplit_kernel(
    const float* __restrict__ W_hh, unsigned short* __restrict__ Wr) {
  int row = blockIdx.x;                 // 0..1535
  int g = row >> 9;
  int jg = row & 511;
  int jb = jg >> 5, jl = jg & 31;
  size_t dst = ((size_t)jb * 96 + g * 32 + jl) * 512;
  for (int k = threadIdx.x; k < 512; k += 256) {
    float w = W_hh[(size_t)row * 512 + k];
    unsigned short g0 = f2h_(w);
    float r1 = (w - h2f_(g0)) * 4096.0f;
    unsigned short g1 = f2h_(r1);
    Wr[dst + k] = g0;
    Wr[WPLANE + dst + k] = g1;
  }
}

// split h_T (512) into sT[2][512] fp16 planes
__global__ __launch_bounds__(256) void hsplit_kernel(
    const float* __restrict__ h_T, unsigned short* __restrict__ sT) {
  int i = threadIdx.x;
  for (int j = i; j < 512; j += 256) {
    float v = h_T[j];
    unsigned short f0 = f2h_(v);
    float r1 = (v - h2f_(f0)) * 4096.0f;
    sT[j] = f0;
    sT[512 + j] = f2h_(r1);
  }
}

// persistent encoder GRU; round-3 flag barrier, co-located on one XCD:
// launch ENC_BLOCKS*8 blocks, only b%8==0 work (block->XCD = b&7 heuristic;
// correctness does not depend on it — flags are agent-scope).
__global__ __launch_bounds__(256) void enc_gru_kernel(
    const float* __restrict__ enc_gi, const float* __restrict__ W_hh,
    const float* __restrict__ b_hh, float* __restrict__ ghbuf,
    unsigned* __restrict__ flags, float* __restrict__ h_T) {
  if (blockIdx.x & 7) return;
  int blk = blockIdx.x >> 3;
  __shared__ __align__(16) float hs[HIDDEN];
  int tid = threadIdx.x;
  int gtid = blk * 256 + tid;
  int row = gtid >> 3;
  int sub = gtid & 7;

  float w[64];
  const float* wp = W_hh + (size_t)row * HIDDEN + sub * 64;
  #pragma unroll
  for (int i = 0; i < 16; i++) {
    float4 v = *(const float4*)(wp + 4 * i);
    w[4 * i + 0] = v.x; w[4 * i + 1] = v.y; w[4 * i + 2] = v.z; w[4 * i + 3] = v.w;
  }
  if (tid < 128) *(float4*)&hs[tid * 4] = make_float4(0.f, 0.f, 0.f, 0.f);
  float bhr0 = b_hh[tid],       bhz0 = b_hh[512 + tid],  bhn0 = b_hh[1024 + tid];
  float bhr1 = b_hh[256 + tid], bhz1 = b_hh[768 + tid],  bhn1 = b_hh[1280 + tid];
  __syncthreads();

  for (int t = 0; t < HIST; t++) {
    float p = 0.0f;
    const float4* hv = (const float4*)&hs[sub * 64];
    #pragma unroll
    for (int i = 0; i < 16; i++) {
      float4 v = hv[i];
      p += w[4 * i + 0] * v.x + w[4 * i + 1] * v.y +
           w[4 * i + 2] * v.z + w[4 * i + 3] * v.w;
    }
    p += __shfl_xor(p, 1, 64);
    p += __shfl_xor(p, 2, 64);
    p += __shfl_xor(p, 4, 64);
    int par = t & 1;
    if (sub == 0)
      __hip_atomic_store(&ghbuf[par * 1536 + row], p, __ATOMIC_RELAXED,
                         __HIP_MEMORY_SCOPE_AGENT);
    __syncthreads();
    if (tid == 0)
      __hip_atomic_store(&flags[blk * 16], (unsigned)(t + 1),
                         __ATOMIC_RELEASE, __HIP_MEMORY_SCOPE_AGENT);
    if (tid < ENC_BLOCKS) {
      while (__hip_atomic_load(&flags[tid * 16], __ATOMIC_ACQUIRE,
                               __HIP_MEMORY_SCOPE_AGENT) < (unsigned)(t + 1))
        __builtin_amdgcn_s_sleep(1);
    }
    __syncthreads();
    float hn0, hn1;
    {
      int j = tid;
      float ghr = __hip_atomic_load(&ghbuf[par * 1536 + j], __ATOMIC_RELAXED, __HIP_MEMORY_SCOPE_AGENT);
      float ghz = __hip_atomic_load(&ghbuf[par * 1536 + 512 + j], __ATOMIC_RELAXED, __HIP_MEMORY_SCOPE_AGENT);
      float ghn = __hip_atomic_load(&ghbuf[par * 1536 + 1024 + j], __ATOMIC_RELAXED, __HIP_MEMORY_SCOPE_AGENT);
      float gir = enc_gi[(size_t)t * 1536 + j];
      float giz = enc_gi[(size_t)t * 1536 + 512 + j];
      float gin = enc_gi[(size_t)t * 1536 + 1024 + j];
      float r = sigmoid_(gir + (ghr + bhr0));
      float z = sigmoid_(giz + (ghz + bhz0));
      float n = tanhf(gin + r * (ghn + bhn0));
      hn0 = (1.0f - z) * n + z * hs[j];
    }
    {
      int j = tid + 256;
      float ghr = __hip_atomic_load(&ghbuf[par * 1536 + j], __ATOMIC_RELAXED, __HIP_MEMORY_SCOPE_AGENT);
      float ghz = __hip_atomic_load(&ghbuf[par * 1536 + 512 + j], __ATOMIC_RELAXED, __HIP_MEMORY_SCOPE_AGENT);
      float ghn = __hip_atomic_load(&ghbuf[par * 1536 + 1024 + j], __ATOMIC_RELAXED, __HIP_MEMORY_SCOPE_AGENT);
      float gir = enc_gi[(size_t)t * 1536 + j];
      float giz = enc_gi[(size_t)t * 1536 + 512 + j];
      float gin = enc_gi[(size_t)t * 1536 + 1024 + j];
      float r = sigmoid_(gir + (ghr + bhr1));
      float z = sigmoid_(giz + (ghz + bhz1));
      float n = tanhf(gin + r * (ghn + bhn1));
      hn1 = (1.0f - z) * n + z * hs[j];
    }
    hs[tid] = hn0;
    hs[tid + 256] = hn1;
    __syncthreads();
  }
  if (blk == 0 && tid < 128)
    *(float4*)&h_T[tid * 4] = *(float4*)&hs[tid * 4];
}

// ---------------------------------------------------------------------------
// Sample-resident persistent decoder. 256 blocks x 256 threads, 1 block/CU.
// Block owns samples [b*32, b*32+32). h in LDS (2 fp16 planes, dbuf).
// Per step: each wave handles jb = wave*4 + jj (4 slabs of 32 j x 3 gates),
// M=32 x N=96 x K=512 GEMM (A from LDS, B from L2-resident Wr), epilogue
// writes h_new planes + per-jb head partials; then RNG (8 samples/wave).
// LDS index swizzle: element (s, k) stored at chunk (k>>3)^(s&7).
// ---------------------------------------------------------------------------
__global__ __launch_bounds__(256, 1) void dec_fused(
    const unsigned short* __restrict__ sT, const unsigned short* __restrict__ Wr,
    const float* __restrict__ giy, const float* __restrict__ b_hh,
    const float* __restrict__ W_ih, const float* __restrict__ x,
    const float* __restrict__ W_df, const float* __restrict__ b_df,
    const float* __restrict__ W_loc, const float* __restrict__ b_loc,
    const float* __restrict__ W_sc, const float* __restrict__ b_sc,
    const float* __restrict__ scale_p, float* __restrict__ out) {
  __shared__ __align__(16) unsigned short hb[2][2][32][512];  // 128 KB
  __shared__ float pbuf[16][32][3];                           // 6 KB
  __shared__ float tgt_l[32];
  int tid = threadIdx.x;
  int lane = tid & 63;
  int wave = tid >> 6;
  int q = lane >> 4, c = lane & 15;
  int s0 = blockIdx.x * 32;

  float xlast = x[HIST - 1];
  float scale = scale_p[0];

  // init h (sT broadcast to all 32 samples) and tgt
  if (tid < 32) tgt_l[tid] = xlast;
  for (int idx = tid; idx < 1024; idx += 256) {
    int sp = idx >> 9, kk = idx & 511;
    unsigned short v = sT[sp * 512 + kk];
    int ch = kk >> 3, e = kk & 7;
    #pragma unroll
    for (int s = 0; s < 32; s++)
      hb[0][sp][s][((ch ^ (s & 7)) << 3) | e] = v;
  }
  __syncthreads();

  for (int k = 0; k < PRED; k++) {
    int cur = k & 1, nxt = cur ^ 1;
    const float* giy_k = giy + (size_t)k * 1536;

    for (int jj = 0; jj < 4; jj++) {
      int jb = wave * 4 + jj;

      // B row base pointers (n = g*2+jt)
      const unsigned short* Brow[6];
      #pragma unroll
      for (int n = 0; n < 6; n++) {
        int row = jb * 96 + (n >> 1) * 32 + (n & 1) * 16 + c;
        Brow[n] = Wr + (size_t)row * 512 + q * 8;
      }

      f32x4 am[2][6], ac[2][6];
      #pragma unroll
      for (int mt = 0; mt < 2; mt++)
        #pragma unroll
        for (int n = 0; n < 6; n++) {
          am[mt][n] = (f32x4){0.f, 0.f, 0.f, 0.f};
          ac[mt][n] = (f32x4){0.f, 0.f, 0.f, 0.f};
        }

      // initial A (kb=0) + B (kb=0)
      half8 Ah[2][2], An[2][2], Bc[6][2], Bn[6][2];
      #pragma unroll
      for (int mt = 0; mt < 2; mt++) {
        int m = mt * 16 + c;
        int off = (((0 * 4 + q) ^ (m & 7)) << 3);
        Ah[mt][0] = *(const half8*)&hb[cur][0][m][off];
        Ah[mt][1] = *(const half8*)&hb[cur][1][m][off];
      }
      #pragma unroll
      for (int n = 0; n < 6; n++) {
        Bc[n][0] = *(const half8*)(Brow[n]);
        Bc[n][1] = *(const half8*)(Brow[n] + WPLANE);
      }

      for (int kbi = 0; kbi < 16; kbi++) {
        if (kbi < 15) {
          #pragma unroll
          for (int mt = 0; mt < 2; mt++) {
            int m = mt * 16 + c;
            int off = ((((kbi + 1) * 4 + q) ^ (m & 7)) << 3);
            An[mt][0] = *(const half8*)&hb[cur][0][m][off];
            An[mt][1] = *(const half8*)&hb[cur][1][m][off];
          }
          #pragma unroll
          for (int n = 0; n < 6; n++) {
            Bn[n][0] = *(const half8*)(Brow[n] + (kbi + 1) * 32);
            Bn[n][1] = *(const half8*)(Brow[n] + WPLANE + (kbi + 1) * 32);
          }
        }
        #pragma unroll
        for (int mt = 0; mt < 2; mt++) {
          #pragma unroll
          for (int n = 0; n < 6; n++) {
            am[mt][n] = __builtin_amdgcn_mfma_f32_16x16x32_f16(Ah[mt][0], Bc[n][0], am[mt][n], 0, 0, 0);
            ac[mt][n] = __builtin_amdgcn_mfma_f32_16x16x32_f16(Ah[mt][0], Bc[n][1], ac[mt][n], 0, 0, 0);
            ac[mt][n] = __builtin_amdgcn_mfma_f32_16x16x32_f16(Ah[mt][1], Bc[n][0], ac[mt][n], 0, 0, 0);
          }
        }
        if (kbi < 15) {
          #pragma unroll
          for (int mt = 0; mt < 2; mt++) {
            Ah[mt][0] = An[mt][0];
            Ah[mt][1] = An[mt][1];
          }
          #pragma unroll
          for (int n = 0; n < 6; n++) {
            Bc[n][0] = Bn[n][0];
            Bc[n][1] = Bn[n][1];
          }
        }
      }

      // epilogue for this jb: gates + h update + head partials
      float gy[2][3], w0[2][3], bh[2][3], wh[2][3];
      #pragma unroll
      for (int jt = 0; jt < 2; jt++) {
        int j = jb * 32 + jt * 16 + c;
        gy[jt][0] = giy_k[j]; gy[jt][1] = giy_k[512 + j]; gy[jt][2] = giy_k[1024 + j];
        w0[jt][0] = W_ih[(size_t)j * 41];
        w0[jt][1] = W_ih[(size_t)(512 + j) * 41];
        w0[jt][2] = W_ih[(size_t)(1024 + j) * 41];
        bh[jt][0] = b_hh[j]; bh[jt][1] = b_hh[512 + j]; bh[jt][2] = b_hh[1024 + j];
        wh[jt][0] = W_df[j]; wh[jt][1] = W_loc[j]; wh[jt][2] = W_sc[j];
      }
      #pragma unroll
      for (int mt = 0; mt < 2; mt++) {
        #pragma unroll
        for (int reg = 0; reg < 4; reg++) {
          int s = mt * 16 + q * 4 + reg;
          float tg = tgt_l[s];
          float vdt[2], vlt[2], vst[2];
          #pragma unroll
          for (int jt = 0; jt < 2; jt++) {
            int n0 = jt, n1 = 2 + jt, n2 = 4 + jt;   // r, z, n tiles
            int j = jb * 32 + jt * 16 + c;
            int swz = (((j >> 3) ^ (s & 7)) << 3) | (j & 7);
            float h_old = h2f_(hb[cur][0][s][swz]) +
                          h2f_(hb[cur][1][s][swz]) * INV4096;
            float ghr = am[mt][n0][reg] + ac[mt][n0][reg] * INV4096;
            float ghz = am[mt][n1][reg] + ac[mt][n1][reg] * INV4096;
            float ghn = am[mt][n2][reg] + ac[mt][n2][reg] * INV4096;
            float gr = (gy[jt][0] + w0[jt][0] * tg) + (ghr + bh[jt][0]);
            float gz = (gy[jt][1] + w0[jt][1] * tg) + (ghz + bh[jt][1]);
            float gn_i = gy[jt][2] + w0[jt][2] * tg;
            float gn_h = ghn + bh[jt][2];
            float r_ = sigmoid_(gr);
            float z_ = sigmoid_(gz);
            float n_ = tanhf(gn_i + r_ * gn_h);
            float hn = (1.0f - z_) * n_ + z_ * h_old;
            unsigned short f0 = f2h_(hn);
            float r1 = (hn - h2f_(f0)) * 4096.0f;
            hb[nxt][0][s][swz] = f0;
            hb[nxt][1][s][swz] = f2h_(r1);
            float vd = hn * wh[jt][0], vl = hn * wh[jt][1], vs = hn * wh[jt][2];
            #pragma unroll
            for (int o = 1; o < 16; o <<= 1) {
              vd += __shfl_xor(vd, o, 64);
              vl += __shfl_xor(vl, o, 64);
              vs += __shfl_xor(vs, o, 64);
            }
            vdt[jt] = vd; vlt[jt] = vl; vst[jt] = vs;
          }
          if (c == 0) {
            pbuf[jb][s][0] = vdt[0] + vdt[1];
            pbuf[jb][s][1] = vlt[0] + vlt[1];
            pbuf[jb][s][2] = vst[0] + vst[1];
          }
        }
      }
    }

    __syncthreads();   // h_new + pbuf complete

    // heads + RNG: 8 samples per wave
    {
      #pragma clang fp contract(off)
      if (lane < 8) {
        int sl = wave * 8 + lane;
        float adf = 0.f, alo = 0.f, asc = 0.f;
        #pragma unroll
        for (int jb = 0; jb < 16; jb++) {
          adf += pbuf[jb][sl][0];
          alo += pbuf[jb][sl][1];
          asc += pbuf[jb][sl][2];
        }
        float df = 2.0f + softplus_(adf + b_df[0]);
        float loc = alo + b_loc[0];
        float sc = softplus_(asc + b_sc[0]);
        float eps = sample_t_eps_(k, s0 + sl, df);
        float smp = (loc + sc * eps) * scale;
        out[(size_t)(s0 + sl) * PRED + k] = smp;
        tgt_l[sl] = smp;
      }
    }
    __syncthreads();   // tgt_l ready; pbuf free
  }
}

// ------------------------------- launcher ----------------------------------
extern "C" void kernel_launch(void* const* d_in, const int* in_sizes, int n_in,
                              void* d_out, int out_size, void* d_ws, size_t ws_size,
                              hipStream_t stream) {
  const float* x      = (const float*)d_in[0];
  const float* x_mark = (const float*)d_in[1];
  const float* y_mark = (const float*)d_in[2];
  const float* W_emb  = (const float*)d_in[4];
  const float* b_emb  = (const float*)d_in[5];
  const float* W_ih   = (const float*)d_in[6];
  const float* W_hh   = (const float*)d_in[7];
  const float* b_ih   = (const float*)d_in[8];
  const float* b_hh   = (const float*)d_in[9];
  const float* W_df   = (const float*)d_in[10];
  const float* b_df   = (const float*)d_in[11];
  const float* W_loc  = (const float*)d_in[12];
  const float* b_loc  = (const float*)d_in[13];
  const float* W_sc   = (const float*)d_in[14];
  const float* b_sc   = (const float*)d_in[15];
  float* out = (float*)d_out;

  float* w = (float*)d_ws;
  unsigned short* Wr = (unsigned short*)(w);        // 2*1536*512 sh = 393216 fl
  float* enc_gi = w + 393216;               // 336*1536 -> ends 909312
  float* giy    = w + 909312;               // 48*1536 -> 983040
  float* tfe    = w + 983040;               // 336*40 -> 996480
  float* emb_y  = w + 996480;               // 48*40 -> 998400
  float* ghbuf  = w + 998400;               // 2*1536 -> 1001472
  float* h_T    = w + 1001472;              // 512 -> 1001984
  unsigned short* sT = (unsigned short*)(w + 1001984);  // 2*512 sh -> 1002496
  float* scale_p = w + 1002496;             // 1
  unsigned* flags = (unsigned*)(w + 1002500);  // 48*16 ints

  prep_kernel<<<1, 256, 0, stream>>>(x, x_mark, y_mark, W_emb, b_emb,
                                     scale_p, tfe, emb_y, flags);
  enc_gi_kernel<<<HIST, 256, 0, stream>>>(x, tfe, W_ih, b_ih, scale_p, enc_gi);
  giy_kernel<<<PRED, 256, 0, stream>>>(emb_y, W_ih, b_ih, giy);
  wsplit_kernel<<<1536, 256, 0, stream>>>(W_hh, Wr);
  enc_gru_kernel<<<ENC_BLOCKS * 8, 256, 0, stream>>>(enc_gi, W_hh, b_hh,
                                                     ghbuf, flags, h_T);
  hsplit_kernel<<<1, 256, 0, stream>>>(h_T, sT);

  dec_fused<<<256, 256, 0, stream>>>(
      sT, Wr, giy, b_hh, W_ih, x, W_df, b_df, W_loc, b_loc, W_sc, b_sc,
      scale_p, out);
}

// Round 11
// 6140.767 us; speedup vs baseline: 1.6586x; 1.6586x over previous
//
#include <hip/hip_runtime.h>
#include <cmath>

// ---------------------------------------------------------------------------
// DeepAR sampling on MI355X. Round 11: sample-resident decoder, fixed.
//  - r10 post-mortem: FETCH 16 MB (dataflow right) but 1 block x 4 waves/CU
//    = 1 wave/SIMD -> latency-starved (123 us/step vs 23 us L2 floor), and
//    encoder co-location regressed it to ~4 ms.
//  - Fix 1: encoder reverted to round-9 48-block version (known 1.27 ms).
//  - Fix 2: dec_fused 256 -> 512 threads (8 waves/CU, 2/SIMD): wave owns
//    2 jb slabs not 4. All arithmetic orders identical -> absmax 1.492188.
//  - h in LDS (128 KB dbuf), weights streamed from per-XCD L2, no grid
//    barriers, no per-step launches.
// ---------------------------------------------------------------------------

#define JAX_PARTITIONABLE 1

#define HIDDEN 512
#define EMB 40
#define HIST 336
#define PRED 48
#define S_N 8192
#define ENC_BLOCKS 48

#define WPLANE (1536 * 512)     // shorts per W split plane
#define INV4096 (1.0f / 4096.0f)

typedef __attribute__((ext_vector_type(8))) _Float16 half8;
typedef __attribute__((ext_vector_type(4))) float f32x4;

// ------------------------------- threefry ----------------------------------
struct KeyPair { unsigned a, b; };

__device__ __forceinline__ unsigned rotl32_(unsigned v, unsigned s) {
  return (v << s) | (v >> (32u - s));
}

__device__ __forceinline__ KeyPair tf2x32(KeyPair k, unsigned x0, unsigned x1) {
  unsigned ks0 = k.a, ks1 = k.b, ks2 = ks0 ^ ks1 ^ 0x1BD11BDAu;
  x0 += ks0; x1 += ks1;
#define TF_R(r) { x0 += x1; x1 = rotl32_(x1, r); x1 ^= x0; }
  TF_R(13u) TF_R(15u) TF_R(26u) TF_R(6u)  x0 += ks1; x1 += ks2 + 1u;
  TF_R(17u) TF_R(29u) TF_R(16u) TF_R(24u) x0 += ks2; x1 += ks0 + 2u;
  TF_R(13u) TF_R(15u) TF_R(26u) TF_R(6u)  x0 += ks0; x1 += ks1 + 3u;
  TF_R(17u) TF_R(29u) TF_R(16u) TF_R(24u) x0 += ks1; x1 += ks2 + 4u;
  TF_R(13u) TF_R(15u) TF_R(26u) TF_R(6u)  x0 += ks2; x1 += ks0 + 5u;
#undef TF_R
  KeyPair r; r.a = x0; r.b = x1; return r;
}

__device__ __forceinline__ void split2_(KeyPair key, KeyPair& r0, KeyPair& r1) {
#if JAX_PARTITIONABLE
  r0 = tf2x32(key, 0u, 0u);
  r1 = tf2x32(key, 0u, 1u);
#else
  KeyPair p0 = tf2x32(key, 0u, 2u);
  KeyPair p1 = tf2x32(key, 1u, 3u);
  r0.a = p0.a; r0.b = p1.a;
  r1.a = p0.b; r1.b = p1.b;
#endif
}

__device__ __forceinline__ void split3_(KeyPair key, KeyPair& r0, KeyPair& r1, KeyPair& r2) {
#if JAX_PARTITIONABLE
  r0 = tf2x32(key, 0u, 0u);
  r1 = tf2x32(key, 0u, 1u);
  r2 = tf2x32(key, 0u, 2u);
#else
  KeyPair p0 = tf2x32(key, 0u, 3u);
  KeyPair p1 = tf2x32(key, 1u, 4u);
  KeyPair p2 = tf2x32(key, 2u, 5u);
  r0.a = p0.a; r0.b = p1.a;
  r1.a = p2.a; r1.b = p0.b;
  r2.a = p1.b; r2.b = p2.b;
#endif
}

__device__ __forceinline__ unsigned scalar_bits_(KeyPair key) {
#if JAX_PARTITIONABLE
  KeyPair p = tf2x32(key, 0u, 0u);
  return p.a ^ p.b;
#else
  return tf2x32(key, 0u, 0u).a;
#endif
}

__device__ __forceinline__ unsigned batch_bits_8192_(KeyPair key, int s) {
#if JAX_PARTITIONABLE
  KeyPair p = tf2x32(key, 0u, (unsigned)s);
  return p.a ^ p.b;
#else
  if (s < 4096) return tf2x32(key, (unsigned)s, (unsigned)(4096 + s)).a;
  return tf2x32(key, (unsigned)(s - 4096), (unsigned)s).b;
#endif
}

__device__ __forceinline__ KeyPair subkey_of_8192_(KeyPair key, int s) {
#if JAX_PARTITIONABLE
  return tf2x32(key, 0u, (unsigned)s);
#else
  KeyPair r;
  if (s < 4096) {
    r.a = tf2x32(key, (unsigned)(2 * s),     (unsigned)(8192 + 2 * s)).a;
    r.b = tf2x32(key, (unsigned)(2 * s + 1), (unsigned)(8192 + 2 * s + 1)).a;
  } else {
    int m = 2 * s - 8192;
    r.a = tf2x32(key, (unsigned)m,       (unsigned)(m + 8192)).b;
    r.b = tf2x32(key, (unsigned)(m + 1), (unsigned)(m + 1 + 8192)).b;
  }
  return r;
#endif
}

// ------------------------- fp32 numerics (XLA-matched) ---------------------
__device__ __forceinline__ float acc_logf_(float x) {
  return (float)log((double)x);
}
__device__ __forceinline__ float acc_expf_(float x) {
  return (float)exp((double)x);
}

__device__ __forceinline__ float bits_to_uniform01_(unsigned bits) {
  return __uint_as_float((bits >> 9) | 0x3F800000u) - 1.0f;
}

__device__ __forceinline__ float xla_log1pf_(float t) {
  #pragma clang fp contract(off)
  float small_ = (1.0f + (-0.5f) * t) * t;
  float large_ = acc_logf_(t + 1.0f);
  return (fabsf(t) < 1e-4f) ? small_ : large_;
}

__device__ float xla_erfinv_(float x) {
  #pragma clang fp contract(off)
  float w = -xla_log1pf_(-(x * x));
  float p;
  if (w < 5.0f) {
    float ww = w - 2.5f;
    p = 2.81022636e-08f;
    p = 3.43273939e-07f + p * ww;
    p = -3.5233877e-06f + p * ww;
    p = -4.39150654e-06f + p * ww;
    p = 0.00021858087f + p * ww;
    p = -0.00125372503f + p * ww;
    p = -0.00417768164f + p * ww;
    p = 0.246640727f + p * ww;
    p = 1.50140941f + p * ww;
  } else {
    float ww = sqrtf(w) - 3.0f;
    p = -0.000200214257f;
    p = 0.000100950558f + p * ww;
    p = 0.00134934322f + p * ww;
    p = -0.00367342844f + p * ww;
    p = 0.00573950773f + p * ww;
    p = -0.0076224613f + p * ww;
    p = 0.00943887047f + p * ww;
    p = 1.00167406f + p * ww;
    p = 2.83297682f + p * ww;
  }
  return p * x;
}

__device__ float bits_to_normal_(unsigned bits) {
  #pragma clang fp contract(off)
  const float lo = __uint_as_float(0xBF7FFFFFu);
  float f = bits_to_uniform01_(bits);
  float u = f * 2.0f + lo;
  u = fmaxf(lo, u);
  return __uint_as_float(0x3FB504F3u) * xla_erfinv_(u);
}

__device__ __forceinline__ float softplus_(float x) {
  #pragma clang fp contract(off)
  float amax = fmaxf(x, 0.0f);
  float e = acc_expf_(-fabsf(x));
  return amax + xla_log1pf_(e);
}

__device__ __forceinline__ float sigmoid_(float v) { return 1.0f / (1.0f + expf(-v)); }

// fp16 split helpers (round-to-nearest-even via cast)
__device__ __forceinline__ unsigned short f2h_(float f) {
  _Float16 h = (_Float16)f;
  return __builtin_bit_cast(unsigned short, h);
}
__device__ __forceinline__ float h2f_(unsigned short b) {
  return (float)__builtin_bit_cast(_Float16, b);
}

// ------------------------- gamma / student-t sampler -----------------------
__device__ float gamma_sample_(KeyPair gkey, float alpha) {
  #pragma clang fp contract(off)
  const float third = 0.33333334f;
  float d = alpha - third;
  float c = third / sqrtf(d);
  KeyPair key, boost_sub;
  split2_(gkey, key, boost_sub);
  (void)boost_sub;
  float X = 0.0f, V = 1.0f, U = 2.0f;
  for (int guard = 0; guard < 1024; guard++) {
    float X2 = X * X;
    float sq = 1.0f - 0.0331f * (X2 * X2);
    bool cont = false;
    if (U >= sq) {
      float lhs = acc_logf_(U);
      float rhs = (X * 0.5f) + (d * ((1.0f - V) + acc_logf_(V)));
      cont = (lhs >= rhs);
    }
    if (!cont) break;
    KeyPair nkey, xkey, Ukey;
    split3_(key, nkey, xkey, Ukey);
    key = nkey;
    float x, v;
    KeyPair kk = xkey;
    do {
      KeyPair knew, sub;
      split2_(kk, knew, sub);
      kk = knew;
      x = bits_to_normal_(scalar_bits_(sub));
      v = 1.0f + x * c;
    } while (v <= 0.0f);
    X = x * x;
    V = (v * v) * v;
    U = bits_to_uniform01_(scalar_bits_(Ukey));
  }
  return d * V;
}

__device__ float sample_t_eps_(int k, int s, float df) {
  #pragma clang fp contract(off)
  KeyPair base; base.a = 0u; base.b = 42u;
  KeyPair tkey = tf2x32(base, 0u, (unsigned)k);
  KeyPair key_n, key_g;
  split2_(tkey, key_n, key_g);
  float n = bits_to_normal_(batch_bits_8192_(key_n, s));
  KeyPair gkey = subkey_of_8192_(key_g, s);
  float half_df = df * 0.5f;
  float g = gamma_sample_(gkey, half_df);
  return n * sqrtf(half_df / g);
}

// ------------------------------- kernels -----------------------------------

__global__ __launch_bounds__(256) void prep_kernel(
    const float* __restrict__ x, const float* __restrict__ x_mark,
    const float* __restrict__ y_mark, const float* __restrict__ W_emb,
    const float* __restrict__ b_emb, float* __restrict__ scale_p,
    float* __restrict__ tfe, float* __restrict__ emb_y,
    unsigned* __restrict__ flags) {
  int tid = threadIdx.x;
  if (tid == 0) {
    float s = 0.0f;
    for (int t = 0; t < HIST; t++) s += fabsf(x[t]);
    float m = s / 336.0f;
    scale_p[0] = fmaxf(m, 1e-5f);
  }
  for (int i = tid; i < ENC_BLOCKS * 16; i += 256) flags[i] = 0u;
  for (int idx = tid; idx < HIST * EMB; idx += 256) {
    int t = idx / EMB, e = idx % EMB;
    float a = b_emb[e];
    for (int f = 0; f < 4; f++) a += x_mark[t * 4 + f] * W_emb[e * 4 + f];
    tfe[idx] = a;
  }
  for (int idx = tid; idx < PRED * EMB; idx += 256) {
    int kk = idx / EMB, e = idx % EMB;
    float a = b_emb[e];
    for (int f = 0; f < 4; f++) a += y_mark[kk * 4 + f] * W_emb[e * 4 + f];
    emb_y[idx] = a;
  }
}

__global__ __launch_bounds__(256) void enc_gi_kernel(
    const float* __restrict__ x, const float* __restrict__ tfe,
    const float* __restrict__ W_ih, const float* __restrict__ b_ih,
    const float* __restrict__ scale_p, float* __restrict__ enc_gi) {
  __shared__ float fe[EMB];
  __shared__ float xs_s;
  int t = blockIdx.x;
  int tid = threadIdx.x;
  if (tid < EMB) fe[tid] = tfe[t * EMB + tid];
  if (tid == 0) xs_s = x[t] / scale_p[0];
  __syncthreads();
  float xs = xs_s;
  for (int r = tid; r < 3 * HIDDEN; r += 256) {
    const float* wr = W_ih + (size_t)r * 41;
    float a = b_ih[r] + wr[0] * xs;
    #pragma unroll
    for (int e = 0; e < EMB; e++) a += wr[1 + e] * fe[e];
    enc_gi[(size_t)t * 1536 + r] = a;
  }
}

__global__ __launch_bounds__(256) void giy_kernel(
    const float* __restrict__ emb_y, const float* __restrict__ W_ih,
    const float* __restrict__ b_ih, float* __restrict__ giy) {
  __shared__ float fe[EMB];
  int k = blockIdx.x;
  int tid = threadIdx.x;
  if (tid < EMB) fe[tid] = emb_y[k * EMB + tid];
  __syncthreads();
  for (int r = tid; r < 3 * HIDDEN; r += 256) {
    const float* wr = W_ih + (size_t)r * 41;
    float a = b_ih[r];
    #pragma unroll
    for (int e = 0; e < EMB; e++) a += wr[1 + e] * fe[e];
    giy[(size_t)k * 1536 + r] = a;
  }
}

// W_hh -> 2 fp16 split planes: Wr[sp][jb*96 + g*32 + jl][k], row = g*512+jb*32+jl
__global__ __launch_bounds__(256) void wsplit_kernel(
    const float* __restrict__ W_hh, unsigned short* __restrict__ Wr) {
  int row = blockIdx.x;                 // 0..1535
  int g = row >> 9;
  int jg = row & 511;
  int jb = jg >> 5, jl = jg & 31;
  size_t dst = ((size_t)jb * 96 + g * 32 + jl) * 512;
  for (int k = threadIdx.x; k < 512; k += 256) {
    float w = W_hh[(size_t)row * 512 + k];
    unsigned short g0 = f2h_(w);
    float r1 = (w - h2f_(g0)) * 4096.0f;
    unsigned short g1 = f2h_(r1);
    Wr[dst + k] = g0;
    Wr[WPLANE + dst + k] = g1;
  }
}

// split h_T (512) into sT[2][512] fp16 planes
__global__ __launch_bounds__(256) void hsplit_kernel(
    const float* __restrict__ h_T, unsigned short* __restrict__ sT) {
  int i = threadIdx.x;
  for (int j = i; j < 512; j += 256) {
    float v = h_T[j];
    unsigned short f0 = f2h_(v);
    float r1 = (v - h2f_(f0)) * 4096.0f;
    sT[j] = f0;
    sT[512 + j] = f2h_(r1);
  }
}

// persistent encoder GRU; round-3/9 flag-array grid barrier (48 blocks)
__global__ __launch_bounds__(256) void enc_gru_kernel(
    const float* __restrict__ enc_gi, const float* __restrict__ W_hh,
    const float* __restrict__ b_hh, float* __restrict__ ghbuf,
    unsigned* __restrict__ flags, float* __restrict__ h_T) {
  __shared__ __align__(16) float hs[HIDDEN];
  int tid = threadIdx.x;
  int gtid = blockIdx.x * 256 + tid;
  int row = gtid >> 3;
  int sub = gtid & 7;

  float w[64];
  const float* wp = W_hh + (size_t)row * HIDDEN + sub * 64;
  #pragma unroll
  for (int i = 0; i < 16; i++) {
    float4 v = *(const float4*)(wp + 4 * i);
    w[4 * i + 0] = v.x; w[4 * i + 1] = v.y; w[4 * i + 2] = v.z; w[4 * i + 3] = v.w;
  }
  if (tid < 128) *(float4*)&hs[tid * 4] = make_float4(0.f, 0.f, 0.f, 0.f);
  float bhr0 = b_hh[tid],       bhz0 = b_hh[512 + tid],  bhn0 = b_hh[1024 + tid];
  float bhr1 = b_hh[256 + tid], bhz1 = b_hh[768 + tid],  bhn1 = b_hh[1280 + tid];
  __syncthreads();

  for (int t = 0; t < HIST; t++) {
    float p = 0.0f;
    const float4* hv = (const float4*)&hs[sub * 64];
    #pragma unroll
    for (int i = 0; i < 16; i++) {
      float4 v = hv[i];
      p += w[4 * i + 0] * v.x + w[4 * i + 1] * v.y +
           w[4 * i + 2] * v.z + w[4 * i + 3] * v.w;
    }
    p += __shfl_xor(p, 1, 64);
    p += __shfl_xor(p, 2, 64);
    p += __shfl_xor(p, 4, 64);
    int par = t & 1;
    if (sub == 0)
      __hip_atomic_store(&ghbuf[par * 1536 + row], p, __ATOMIC_RELAXED,
                         __HIP_MEMORY_SCOPE_AGENT);
    __syncthreads();
    if (tid == 0)
      __hip_atomic_store(&flags[blockIdx.x * 16], (unsigned)(t + 1),
                         __ATOMIC_RELEASE, __HIP_MEMORY_SCOPE_AGENT);
    if (tid < ENC_BLOCKS) {
      while (__hip_atomic_load(&flags[tid * 16], __ATOMIC_ACQUIRE,
                               __HIP_MEMORY_SCOPE_AGENT) < (unsigned)(t + 1))
        __builtin_amdgcn_s_sleep(1);
    }
    __syncthreads();
    float hn0, hn1;
    {
      int j = tid;
      float ghr = __hip_atomic_load(&ghbuf[par * 1536 + j], __ATOMIC_RELAXED, __HIP_MEMORY_SCOPE_AGENT);
      float ghz = __hip_atomic_load(&ghbuf[par * 1536 + 512 + j], __ATOMIC_RELAXED, __HIP_MEMORY_SCOPE_AGENT);
      float ghn = __hip_atomic_load(&ghbuf[par * 1536 + 1024 + j], __ATOMIC_RELAXED, __HIP_MEMORY_SCOPE_AGENT);
      float gir = enc_gi[(size_t)t * 1536 + j];
      float giz = enc_gi[(size_t)t * 1536 + 512 + j];
      float gin = enc_gi[(size_t)t * 1536 + 1024 + j];
      float r = sigmoid_(gir + (ghr + bhr0));
      float z = sigmoid_(giz + (ghz + bhz0));
      float n = tanhf(gin + r * (ghn + bhn0));
      hn0 = (1.0f - z) * n + z * hs[j];
    }
    {
      int j = tid + 256;
      float ghr = __hip_atomic_load(&ghbuf[par * 1536 + j], __ATOMIC_RELAXED, __HIP_MEMORY_SCOPE_AGENT);
      float ghz = __hip_atomic_load(&ghbuf[par * 1536 + 512 + j], __ATOMIC_RELAXED, __HIP_MEMORY_SCOPE_AGENT);
      float ghn = __hip_atomic_load(&ghbuf[par * 1536 + 1024 + j], __ATOMIC_RELAXED, __HIP_MEMORY_SCOPE_AGENT);
      float gir = enc_gi[(size_t)t * 1536 + j];
      float giz = enc_gi[(size_t)t * 1536 + 512 + j];
      float gin = enc_gi[(size_t)t * 1536 + 1024 + j];
      float r = sigmoid_(gir + (ghr + bhr1));
      float z = sigmoid_(giz + (ghz + bhz1));
      float n = tanhf(gin + r * (ghn + bhn1));
      hn1 = (1.0f - z) * n + z * hs[j];
    }
    hs[tid] = hn0;
    hs[tid + 256] = hn1;
    __syncthreads();
  }
  if (blockIdx.x == 0 && tid < 128)
    *(float4*)&h_T[tid * 4] = *(float4*)&hs[tid * 4];
}

// ---------------------------------------------------------------------------
// Sample-resident persistent decoder. 256 blocks x 512 threads (8 waves/CU,
// 2 per SIMD). Block owns samples [b*32, b*32+32); h in LDS (fp16 2-plane,
// double-buffered). Per step: wave handles jb = wave*2 + jj (jj=0..1),
// M=32 x N=96 x K=512 (A from LDS, B from L2-resident Wr, 1-deep prefetch);
// epilogue writes h_new + per-jb head partials; then RNG (4 samples/wave).
// Arithmetic orders identical to round 10 -> absmax unchanged.
// ---------------------------------------------------------------------------
__global__ __launch_bounds__(512, 1) void dec_fused(
    const unsigned short* __restrict__ sT, const unsigned short* __restrict__ Wr,
    const float* __restrict__ giy, const float* __restrict__ b_hh,
    const float* __restrict__ W_ih, const float* __restrict__ x,
    const float* __restrict__ W_df, const float* __restrict__ b_df,
    const float* __restrict__ W_loc, const float* __restrict__ b_loc,
    const float* __restrict__ W_sc, const float* __restrict__ b_sc,
    const float* __restrict__ scale_p, float* __restrict__ out) {
  __shared__ __align__(16) unsigned short hb[2][2][32][512];  // 128 KB
  __shared__ float pbuf[16][32][3];                           // 6 KB
  __shared__ float tgt_l[32];
  int tid = threadIdx.x;
  int lane = tid & 63;
  int wave = tid >> 6;               // 0..7
  int q = lane >> 4, c = lane & 15;
  int s0 = blockIdx.x * 32;

  float xlast = x[HIST - 1];
  float scale = scale_p[0];

  // init h (sT broadcast to all 32 samples) and tgt
  if (tid < 32) tgt_l[tid] = xlast;
  for (int idx = tid; idx < 1024; idx += 512) {
    int sp = idx >> 9, kk = idx & 511;
    unsigned short v = sT[sp * 512 + kk];
    int ch = kk >> 3, e = kk & 7;
    #pragma unroll
    for (int s = 0; s < 32; s++)
      hb[0][sp][s][((ch ^ (s & 7)) << 3) | e] = v;
  }
  __syncthreads();

  for (int k = 0; k < PRED; k++) {
    int cur = k & 1, nxt = cur ^ 1;
    const float* giy_k = giy + (size_t)k * 1536;

    for (int jj = 0; jj < 2; jj++) {
      int jb = wave * 2 + jj;

      // B row base pointers (n = g*2+jt)
      const unsigned short* Brow[6];
      #pragma unroll
      for (int n = 0; n < 6; n++) {
        int row = jb * 96 + (n >> 1) * 32 + (n & 1) * 16 + c;
        Brow[n] = Wr + (size_t)row * 512 + q * 8;
      }

      f32x4 am[2][6], ac[2][6];
      #pragma unroll
      for (int mt = 0; mt < 2; mt++)
        #pragma unroll
        for (int n = 0; n < 6; n++) {
          am[mt][n] = (f32x4){0.f, 0.f, 0.f, 0.f};
          ac[mt][n] = (f32x4){0.f, 0.f, 0.f, 0.f};
        }

      // initial A (kb=0) + B (kb=0)
      half8 Ah[2][2], An[2][2], Bc[6][2], Bn[6][2];
      #pragma unroll
      for (int mt = 0; mt < 2; mt++) {
        int m = mt * 16 + c;
        int off = (((0 * 4 + q) ^ (m & 7)) << 3);
        Ah[mt][0] = *(const half8*)&hb[cur][0][m][off];
        Ah[mt][1] = *(const half8*)&hb[cur][1][m][off];
      }
      #pragma unroll
      for (int n = 0; n < 6; n++) {
        Bc[n][0] = *(const half8*)(Brow[n]);
        Bc[n][1] = *(const half8*)(Brow[n] + WPLANE);
      }

      for (int kbi = 0; kbi < 16; kbi++) {
        if (kbi < 15) {
          #pragma unroll
          for (int mt = 0; mt < 2; mt++) {
            int m = mt * 16 + c;
            int off = ((((kbi + 1) * 4 + q) ^ (m & 7)) << 3);
            An[mt][0] = *(const half8*)&hb[cur][0][m][off];
            An[mt][1] = *(const half8*)&hb[cur][1][m][off];
          }
          #pragma unroll
          for (int n = 0; n < 6; n++) {
            Bn[n][0] = *(const half8*)(Brow[n] + (kbi + 1) * 32);
            Bn[n][1] = *(const half8*)(Brow[n] + WPLANE + (kbi + 1) * 32);
          }
        }
        #pragma unroll
        for (int mt = 0; mt < 2; mt++) {
          #pragma unroll
          for (int n = 0; n < 6; n++) {
            am[mt][n] = __builtin_amdgcn_mfma_f32_16x16x32_f16(Ah[mt][0], Bc[n][0], am[mt][n], 0, 0, 0);
            ac[mt][n] = __builtin_amdgcn_mfma_f32_16x16x32_f16(Ah[mt][0], Bc[n][1], ac[mt][n], 0, 0, 0);
            ac[mt][n] = __builtin_amdgcn_mfma_f32_16x16x32_f16(Ah[mt][1], Bc[n][0], ac[mt][n], 0, 0, 0);
          }
        }
        if (kbi < 15) {
          #pragma unroll
          for (int mt = 0; mt < 2; mt++) {
            Ah[mt][0] = An[mt][0];
            Ah[mt][1] = An[mt][1];
          }
          #pragma unroll
          for (int n = 0; n < 6; n++) {
            Bc[n][0] = Bn[n][0];
            Bc[n][1] = Bn[n][1];
          }
        }
      }

      // epilogue for this jb: gates + h update + head partials
      float gy[2][3], w0[2][3], bh[2][3], wh[2][3];
      #pragma unroll
      for (int jt = 0; jt < 2; jt++) {
        int j = jb * 32 + jt * 16 + c;
        gy[jt][0] = giy_k[j]; gy[jt][1] = giy_k[512 + j]; gy[jt][2] = giy_k[1024 + j];
        w0[jt][0] = W_ih[(size_t)j * 41];
        w0[jt][1] = W_ih[(size_t)(512 + j) * 41];
        w0[jt][2] = W_ih[(size_t)(1024 + j) * 41];
        bh[jt][0] = b_hh[j]; bh[jt][1] = b_hh[512 + j]; bh[jt][2] = b_hh[1024 + j];
        wh[jt][0] = W_df[j]; wh[jt][1] = W_loc[j]; wh[jt][2] = W_sc[j];
      }
      #pragma unroll
      for (int mt = 0; mt < 2; mt++) {
        #pragma unroll
        for (int reg = 0; reg < 4; reg++) {
          int s = mt * 16 + q * 4 + reg;
          float tg = tgt_l[s];
          float vdt[2], vlt[2], vst[2];
          #pragma unroll
          for (int jt = 0; jt < 2; jt++) {
            int n0 = jt, n1 = 2 + jt, n2 = 4 + jt;   // r, z, n tiles
            int j = jb * 32 + jt * 16 + c;
            int swz = (((j >> 3) ^ (s & 7)) << 3) | (j & 7);
            float h_old = h2f_(hb[cur][0][s][swz]) +
                          h2f_(hb[cur][1][s][swz]) * INV4096;
            float ghr = am[mt][n0][reg] + ac[mt][n0][reg] * INV4096;
            float ghz = am[mt][n1][reg] + ac[mt][n1][reg] * INV4096;
            float ghn = am[mt][n2][reg] + ac[mt][n2][reg] * INV4096;
            float gr = (gy[jt][0] + w0[jt][0] * tg) + (ghr + bh[jt][0]);
            float gz = (gy[jt][1] + w0[jt][1] * tg) + (ghz + bh[jt][1]);
            float gn_i = gy[jt][2] + w0[jt][2] * tg;
            float gn_h = ghn + bh[jt][2];
            float r_ = sigmoid_(gr);
            float z_ = sigmoid_(gz);
            float n_ = tanhf(gn_i + r_ * gn_h);
            float hn = (1.0f - z_) * n_ + z_ * h_old;
            unsigned short f0 = f2h_(hn);
            float r1 = (hn - h2f_(f0)) * 4096.0f;
            hb[nxt][0][s][swz] = f0;
            hb[nxt][1][s][swz] = f2h_(r1);
            float vd = hn * wh[jt][0], vl = hn * wh[jt][1], vs = hn * wh[jt][2];
            #pragma unroll
            for (int o = 1; o < 16; o <<= 1) {
              vd += __shfl_xor(vd, o, 64);
              vl += __shfl_xor(vl, o, 64);
              vs += __shfl_xor(vs, o, 64);
            }
            vdt[jt] = vd; vlt[jt] = vl; vst[jt] = vs;
          }
          if (c == 0) {
            pbuf[jb][s][0] = vdt[0] + vdt[1];
            pbuf[jb][s][1] = vlt[0] + vlt[1];
            pbuf[jb][s][2] = vst[0] + vst[1];
          }
        }
      }
    }

    __syncthreads();   // h_new + pbuf complete

    // heads + RNG: 4 samples per wave
    {
      #pragma clang fp contract(off)
      if (lane < 4) {
        int sl = wave * 4 + lane;
        float adf = 0.f, alo = 0.f, asc = 0.f;
        #pragma unroll
        for (int jb = 0; jb < 16; jb++) {
          adf += pbuf[jb][sl][0];
          alo += pbuf[jb][sl][1];
          asc += pbuf[jb][sl][2];
        }
        float df = 2.0f + softplus_(adf + b_df[0]);
        float loc = alo + b_loc[0];
        float sc = softplus_(asc + b_sc[0]);
        float eps = sample_t_eps_(k, s0 + sl, df);
        float smp = (loc + sc * eps) * scale;
        out[(size_t)(s0 + sl) * PRED + k] = smp;
        tgt_l[sl] = smp;
      }
    }
    __syncthreads();   // tgt_l ready; pbuf free
  }
}

// ------------------------------- launcher ----------------------------------
extern "C" void kernel_launch(void* const* d_in, const int* in_sizes, int n_in,
                              void* d_out, int out_size, void* d_ws, size_t ws_size,
                              hipStream_t stream) {
  const float* x      = (const float*)d_in[0];
  const float* x_mark = (const float*)d_in[1];
  const float* y_mark = (const float*)d_in[2];
  const float* W_emb  = (const float*)d_in[4];
  const float* b_emb  = (const float*)d_in[5];
  const float* W_ih   = (const float*)d_in[6];
  const float* W_hh   = (const float*)d_in[7];
  const float* b_ih   = (const float*)d_in[8];
  const float* b_hh   = (const float*)d_in[9];
  const float* W_df   = (const float*)d_in[10];
  const float* b_df   = (const float*)d_in[11];
  const float* W_loc  = (const float*)d_in[12];
  const float* b_loc  = (const float*)d_in[13];
  const float* W_sc   = (const float*)d_in[14];
  const float* b_sc   = (const float*)d_in[15];
  float* out = (float*)d_out;

  float* w = (float*)d_ws;
  unsigned short* Wr = (unsigned short*)(w);        // 2*1536*512 sh = 393216 fl
  float* enc_gi = w + 393216;               // 336*1536 -> ends 909312
  float* giy    = w + 909312;               // 48*1536 -> 983040
  float* tfe    = w + 983040;               // 336*40 -> 996480
  float* emb_y  = w + 996480;               // 48*40 -> 998400
  float* ghbuf  = w + 998400;               // 2*1536 -> 1001472
  float* h_T    = w + 1001472;              // 512 -> 1001984
  unsigned short* sT = (unsigned short*)(w + 1001984);  // 2*512 sh -> 1002496
  float* scale_p = w + 1002496;             // 1
  unsigned* flags = (unsigned*)(w + 1002500);  // 48*16 ints

  prep_kernel<<<1, 256, 0, stream>>>(x, x_mark, y_mark, W_emb, b_emb,
                                     scale_p, tfe, emb_y, flags);
  enc_gi_kernel<<<HIST, 256, 0, stream>>>(x, tfe, W_ih, b_ih, scale_p, enc_gi);
  giy_kernel<<<PRED, 256, 0, stream>>>(emb_y, W_ih, b_ih, giy);
  wsplit_kernel<<<1536, 256, 0, stream>>>(W_hh, Wr);
  enc_gru_kernel<<<ENC_BLOCKS, 256, 0, stream>>>(enc_gi, W_hh, b_hh, ghbuf,
                                                 flags, h_T);
  hsplit_kernel<<<1, 256, 0, stream>>>(h_T, sT);

  dec_fused<<<256, 512, 0, stream>>>(
      sT, Wr, giy, b_hh, W_ih, x, W_df, b_df, W_loc, b_loc, W_sc, b_sc,
      scale_p, out);
}